// Round 3
// baseline (114.879 us; speedup 1.0000x reference)
//
#include <hip/hip_runtime.h>

// Conv4d implicit GEMM, v3.
// wprep: weights f32 -> bf16 in MFMA-fragment order Wg[off][rt][ks][lane][8].
// sprep: input f32 -> bf16 slabs S[(b,w',x')][rem=y'*18+z'][ci swizzled] == exact LDS image.
// main:  block = (b, x, w-pair), 512 thr / 8 waves. Waves 0-3 -> output w0, waves 4-7 -> w0+1.
//        12 slabs (4 w' x 3 kx) double-buffered in LDS; stage(s+1) issued before compute(s),
//        one vmcnt(0)+barrier per slab (T3 minimal 2-phase). A-frags direct global->VGPR.
//        Grid 256 = 1 block/CU, bijective XCD swizzle for slab L2 reuse.

typedef __attribute__((ext_vector_type(8))) short bf16x8;
typedef __attribute__((ext_vector_type(4))) float f32x4;
typedef __attribute__((ext_vector_type(8))) unsigned short ushort8;
typedef unsigned short u16;
typedef unsigned int u32;

#define S_OFF_BYTES 663552u          // Wg = 81*4096 u16
#define WS_NEEDED   27537408u        // + 648 slabs * 41472 B

__device__ __forceinline__ u16 f2bf(float f) {
    u32 u = __float_as_uint(f);
    u += 0x7FFFu + ((u >> 16) & 1u);   // RNE
    return (u16)(u >> 16);
}

// ---------------- pre-pass 1: weights ----------------
__global__ __launch_bounds__(256) void wprep(const float* __restrict__ ker, u16* __restrict__ wg) {
    const int g = blockIdx.x * 256 + threadIdx.x;      // 0..41471
    const int l = g & 63, ks = (g >> 6) & 1, rt = (g >> 7) & 3, off = g >> 9;
    const int co  = rt * 16 + (l & 15);
    const int ci0 = ks * 32 + (l >> 4) * 8;
    const float* p = ker + (size_t)off * 4096 + co;
    ushort8 v;
#pragma unroll
    for (int e = 0; e < 8; ++e) v[e] = f2bf(p[(size_t)(ci0 + e) * 64]);
    *(ushort8*)(wg + (size_t)g * 8) = v;
}

// ---------------- pre-pass 2: input slabs ----------------
__global__ __launch_bounds__(256) void sprep(const float* __restrict__ in, u16* __restrict__ s) {
    __shared__ u16 L[64 * 330];
    const int blk = blockIdx.x;                        // 648 = 2*18*18
    const int b = blk / 324, wx = blk - b * 324;
    const float* src = in + (size_t)b * 6718464 + (wx / 18) * 5832 + (wx % 18) * 324;
    const int t = threadIdx.x;
    for (int i = t; i < 5184; i += 256) {
        const int ci = i / 81, j = i - ci * 81;
        float4 v = *(const float4*)(src + (size_t)ci * 104976 + j * 4);
        u32* q = (u32*)&L[ci * 330 + j * 4];
        q[0] = f2bf(v.x) | ((u32)f2bf(v.y) << 16);
        q[1] = f2bf(v.z) | ((u32)f2bf(v.w) << 16);
    }
    __syncthreads();
    u16* dst = s + (size_t)blk * 20736;
    for (int g = t; g < 2592; g += 256) {
        const int rem = g >> 3, gi = g & 7;
        const int a = gi ^ (rem & 7);
        ushort8 v;
#pragma unroll
        for (int e = 0; e < 8; ++e) v[e] = L[(a * 8 + e) * 330 + rem];
        *(ushort8*)(dst + rem * 64 + gi * 8) = v;
    }
}

// ---------------- main ----------------
__global__ __launch_bounds__(512, 2)
void conv4d_main(const u16* __restrict__ wg, const u16* __restrict__ s, float* __restrict__ out) {
    __shared__ u16 T[2][324 * 64];                     // 2 x 41472 B

    // bijective XCD swizzle (256 % 8 == 0): 32 consecutive blocks per XCD
    const int bid = blockIdx.x;
    const int bs  = (bid & 7) * 32 + (bid >> 3);
    const int b   = bs >> 7;
    const int x   = (bs >> 3) & 15;
    const int w0  = (bs & 7) * 2;

    const int t  = threadIdx.x, wv = t >> 6, l = t & 63;
    const int g  = wv >> 2;            // wave group: output w = w0 + g
    const int lw = wv & 3;             // y-tile owner within group
    const int lg = l >> 4, ll = l & 15;

    f32x4 acc[4][4];
#pragma unroll
    for (int i = 0; i < 4; ++i)
#pragma unroll
        for (int j = 0; j < 4; ++j) acc[i][j] = (f32x4){0.f, 0.f, 0.f, 0.f};

    const u16* sb = s + (size_t)b * 324 * 20736 + (size_t)x * 20736;

    // slab si: kx = si>>2, dw = si&3 -> slab (w0+dw, x+kx)
#define STAGE(si, bufi)                                                              \
    do {                                                                             \
        const int kx_ = (si) >> 2, dw_ = (si) & 3;                                   \
        const u16* src_ = sb + (size_t)((w0 + dw_) * 18 + kx_) * 20736;              \
        for (int i_ = t; i_ < 2592; i_ += 512)                                       \
            __builtin_amdgcn_global_load_lds(                                        \
                (const __attribute__((address_space(1))) u32*)(src_ + i_ * 8),       \
                (__attribute__((address_space(3))) u32*)&T[bufi][i_ * 8], 16, 0, 0); \
    } while (0)

    STAGE(0, 0);
    __syncthreads();

    int buf = 0;
    for (int si = 0; si < 12; ++si) {
        if (si + 1 < 12) STAGE(si + 1, buf ^ 1);       // prefetch next slab

        const int kx = si >> 2, dw = si & 3;
        const int kw = dw - g;
        if (kw >= 0 && kw <= 2) {                      // wave-uniform
            const u16* wbase = wg + (size_t)((kw * 3 + kx) * 9) * 4096;
            const u16* Tb = T[buf];
#pragma unroll 3
            for (int sub = 0; sub < 9; ++sub) {
                const int ky = sub / 3, kz = sub - ky * 3;
                const u16* wo = wbase + (size_t)sub * 4096;
#pragma unroll
                for (int ks = 0; ks < 2; ++ks) {
                    bf16x8 a[4];
#pragma unroll
                    for (int rt = 0; rt < 4; ++rt)
                        a[rt] = *(const bf16x8*)(wo + (size_t)((rt * 2 + ks) * 64 + l) * 8);
#pragma unroll
                    for (int ct = 0; ct < 4; ++ct) {
                        const int rem = (lw * 4 + ct + ky) * 18 + ll + kz;
                        const bf16x8 bf = *(const bf16x8*)&Tb[rem * 64 + (((ks * 4 + lg) ^ (rem & 7)) << 3)];
#pragma unroll
                        for (int rt = 0; rt < 4; ++rt)
                            acc[rt][ct] = __builtin_amdgcn_mfma_f32_16x16x32_bf16(a[rt], bf, acc[rt][ct], 0, 0, 0);
                    }
                }
            }
        }
        __syncthreads();                               // drains prefetch vmcnt + compute lgkm
        buf ^= 1;
    }

    float* ob = out + (size_t)b * 4194304 + (size_t)(w0 + g) * 4096 + (size_t)x * 256;
#pragma unroll
    for (int rt = 0; rt < 4; ++rt) {
        const int co0 = rt * 16 + 4 * lg;
#pragma unroll
        for (int ct = 0; ct < 4; ++ct) {
            const int base = (lw * 4 + ct) * 16 + ll;
#pragma unroll
            for (int r = 0; r < 4; ++r)
                ob[(size_t)(co0 + r) * 65536 + base] = acc[rt][ct][r];
        }
    }
#undef STAGE
}

// ---------------- fallback (round-1 kernel, used if ws too small) ----------------
__global__ __launch_bounds__(512, 2)
void conv4d_mfma(const float* __restrict__ in, const float* __restrict__ ker,
                 float* __restrict__ out) {
    __shared__ unsigned short T[18 * 18 * 64];
    __shared__ unsigned short Wt[2][64 * 64];
    const int bx = blockIdx.x;
    const int b = bx >> 8, wsp = (bx >> 4) & 15, x = bx & 15;
    const int t = threadIdx.x, wv = t >> 6, l = t & 63;
    const int lg = l >> 4, ll = l & 15;
    const float* inb = in + (size_t)b * 6718464 + wsp * 5832 + x * 324;
    f32x4 acc[4][2];
#pragma unroll
    for (int i = 0; i < 4; ++i)
#pragma unroll
        for (int j = 0; j < 2; ++j) acc[i][j] = (f32x4){0.f, 0.f, 0.f, 0.f};
#pragma unroll
    for (int f0 = 0; f0 < 4096; f0 += 512) {
        const int f = f0 + t, ci = f >> 6, co = f & 63;
        Wt[0][co * 64 + ((((ci >> 3) ^ (co & 7)) << 3) | (ci & 7))] = f2bf(ker[f]);
    }
    for (int off = 0; off < 81; ++off) {
        const int sub = off % 9;
        if (sub == 0) {
            const int kw = off / 27, kx = (off / 9) % 3;
            const float* p = inb + kw * 5832 + kx * 324;
            for (int f = t; f < 18 * 18 * 64; f += 512) {
                const int ci = f / 324, rem = f - ci * 324, zp = rem % 18;
                T[rem * 64 + ((((ci >> 3) ^ (zp & 7)) << 3) | (ci & 7))] =
                    f2bf(p[(size_t)ci * 104976 + rem]);
            }
        }
        if (off + 1 < 81) {
            const float* p = ker + (off + 1) * 4096;
            unsigned short* wb = Wt[(off + 1) & 1];
#pragma unroll
            for (int f0 = 0; f0 < 4096; f0 += 512) {
                const int f = f0 + t, ci = f >> 6, co = f & 63;
                wb[co * 64 + ((((ci >> 3) ^ (co & 7)) << 3) | (ci & 7))] = f2bf(p[f]);
            }
        }
        if (sub == 0) __syncthreads();
        const unsigned short* Wb = Wt[off & 1];
        const int ky = sub / 3, kz = sub - ky * 3;
        const int zp = ll + kz, zs = zp & 7;
#pragma unroll
        for (int ks = 0; ks < 2; ++ks) {
            bf16x8 af[4];
#pragma unroll
            for (int rt = 0; rt < 4; ++rt)
                af[rt] = *(const bf16x8*)&Wt[off & 1][(rt * 16 + ll) * 64 + (((lg + 4 * ks) ^ (ll & 7)) << 3)];
#pragma unroll
            for (int ct = 0; ct < 2; ++ct) {
                const int rem = (2 * wv + ct + ky) * 18 + zp;
                const bf16x8 bfr = *(const bf16x8*)&T[rem * 64 + (((lg + 4 * ks) ^ zs) << 3)];
#pragma unroll
                for (int rt = 0; rt < 4; ++rt)
                    acc[rt][ct] = __builtin_amdgcn_mfma_f32_16x16x32_bf16(af[rt], bfr, acc[rt][ct], 0, 0, 0);
            }
        }
        __syncthreads();
    }
    float* ob = out + (size_t)b * 4194304 + wsp * 4096 + x * 256;
#pragma unroll
    for (int rt = 0; rt < 4; ++rt) {
        const int co0 = rt * 16 + 4 * lg;
#pragma unroll
        for (int ct = 0; ct < 2; ++ct) {
            const int base = (2 * wv + ct) * 16 + ll;
#pragma unroll
            for (int r = 0; r < 4; ++r)
                ob[(size_t)(co0 + r) * 65536 + base] = acc[rt][ct][r];
        }
    }
}

extern "C" void kernel_launch(void* const* d_in, const int* in_sizes, int n_in,
                              void* d_out, int out_size, void* d_ws, size_t ws_size,
                              hipStream_t stream) {
    const float* in  = (const float*)d_in[0];
    const float* ker = (const float*)d_in[1];
    float* out = (float*)d_out;
    if (ws_size >= (size_t)WS_NEEDED) {
        u16* wg = (u16*)d_ws;
        u16* s  = (u16*)((char*)d_ws + S_OFF_BYTES);
        wprep<<<dim3(162), dim3(256), 0, stream>>>(ker, wg);
        sprep<<<dim3(648), dim3(256), 0, stream>>>(in, s);
        conv4d_main<<<dim3(256), dim3(512), 0, stream>>>(wg, s, out);
    } else {
        conv4d_mfma<<<dim3(512), dim3(512), 0, stream>>>(in, ker, out);
    }
}

// Round 4
// 114.539 us; speedup vs baseline: 1.0030x; 1.0030x over previous
//
#include <hip/hip_runtime.h>

// Conv4d implicit GEMM, v4.
// wprep: weights f32 -> bf16 in MFMA-fragment order Wg[off][rt][ks][lane][8].
// sprep: input f32 -> bf16 half-slabs S[(b,w',x')][ks][rem=y'*18+z'][32 ci], linear
//        (64B rows are naturally bank-conflict-free for the lg-granule fragment read).
// main:  block = (b,w,x), 512 thr / 8 waves, each wave owns y-tiles {2wv, 2wv+1}.
//        18 phases (9 kwx x 2 ks); half-slab (20.7KB) double-buffered: STAGE(p+1)
//        issued before compute(p), one barrier per phase. 2 blocks/CU resident
//        (LDS 41.5KB, VGPR<=128) so barrier drains + L2 latency hide via TLP.
//        A-frags: global->VGPR, ping-pong a[2][4] one sub ahead (static idx, full unroll).

typedef __attribute__((ext_vector_type(8))) short bf16x8;
typedef __attribute__((ext_vector_type(4))) float f32x4;
typedef __attribute__((ext_vector_type(8))) unsigned short ushort8;
typedef unsigned short u16;
typedef unsigned int u32;

#define S_OFF_BYTES 663552u          // Wg = 81*4096 u16
#define WS_NEEDED   27537408u        // + 648 slabs * 41472 B (2 ks-halves x 20736 B)

__device__ __forceinline__ u16 f2bf(float f) {
    u32 u = __float_as_uint(f);
    u += 0x7FFFu + ((u >> 16) & 1u);   // RNE
    return (u16)(u >> 16);
}

// ---------------- pre-pass 1: weights ----------------
__global__ __launch_bounds__(256) void wprep(const float* __restrict__ ker, u16* __restrict__ wg) {
    const int g = blockIdx.x * 256 + threadIdx.x;      // 0..41471
    const int l = g & 63, ks = (g >> 6) & 1, rt = (g >> 7) & 3, off = g >> 9;
    const int co  = rt * 16 + (l & 15);
    const int ci0 = ks * 32 + (l >> 4) * 8;
    const float* p = ker + (size_t)off * 4096 + co;
    ushort8 v;
#pragma unroll
    for (int e = 0; e < 8; ++e) v[e] = f2bf(p[(size_t)(ci0 + e) * 64]);
    *(ushort8*)(wg + (size_t)g * 8) = v;
}

// ---------------- pre-pass 2: input half-slabs ----------------
__global__ __launch_bounds__(256) void sprep(const float* __restrict__ in, u16* __restrict__ s) {
    __shared__ u16 L[64 * 330];                        // [ci][rem padded]
    const int blk = blockIdx.x;                        // 648 = 2*18*18
    const int b = blk / 324, wx = blk - b * 324;
    const float* src = in + (size_t)b * 6718464 + (wx / 18) * 5832 + (wx % 18) * 324;
    const int t = threadIdx.x;
    for (int i = t; i < 5184; i += 256) {              // 64 ci * 81 float4
        const int ci = i / 81, j = i - ci * 81;
        float4 v = *(const float4*)(src + (size_t)ci * 104976 + j * 4);
        u32* q = (u32*)&L[ci * 330 + j * 4];
        q[0] = f2bf(v.x) | ((u32)f2bf(v.y) << 16);
        q[1] = f2bf(v.z) | ((u32)f2bf(v.w) << 16);
    }
    __syncthreads();
    u16* dst = s + (size_t)blk * 20736;                // [ks][rem][32] linear
    for (int i = t; i < 2592; i += 256) {              // 2 ks * 324 rem * 4 granules
        const int ks = i / 1296, r4 = i - ks * 1296;
        const int rem = r4 >> 2, g = r4 & 3;
        ushort8 v;
#pragma unroll
        for (int e = 0; e < 8; ++e) v[e] = L[(ks * 32 + g * 8 + e) * 330 + rem];
        *(ushort8*)(dst + ks * 10368 + rem * 32 + g * 8) = v;  // coalesced 16B/lane
    }
}

// ---------------- main ----------------
__global__ __launch_bounds__(512, 4)
void conv4d_main(const u16* __restrict__ wg, const u16* __restrict__ s, float* __restrict__ out) {
    __shared__ u16 T[2][324 * 32];                     // 2 x 20736 B half-slabs

    // bijective XCD swizzle (512 % 8 == 0): 64 consecutive outputs per XCD
    const int bid = blockIdx.x;
    const int bs  = (bid & 7) * 64 + (bid >> 3);
    const int b   = bs >> 8;
    const int w   = (bs >> 4) & 15;
    const int x   = bs & 15;

    const int t  = threadIdx.x, wv = t >> 6, l = t & 63;
    const int lg = l >> 4, ll = l & 15;

    f32x4 acc[4][2];
#pragma unroll
    for (int i = 0; i < 4; ++i)
#pragma unroll
        for (int j = 0; j < 2; ++j) acc[i][j] = (f32x4){0.f, 0.f, 0.f, 0.f};

    const u16* sb = s + (size_t)(b * 324 + w * 18 + x) * 20736;

    // phase p: kwx = p>>1 (kw*3+kx), ks = p&1
#define STAGE(p, bufi)                                                               \
    do {                                                                             \
        const int kwx_ = (p) >> 1, ks_ = (p) & 1;                                    \
        const int kw_ = kwx_ / 3, kx_ = kwx_ - kw_ * 3;                              \
        const u16* src_ = sb + (size_t)(kw_ * 18 + kx_) * 20736 + ks_ * 10368;       \
        for (int i_ = t; i_ < 1296; i_ += 512)                                       \
            __builtin_amdgcn_global_load_lds(                                        \
                (const __attribute__((address_space(1))) u32*)(src_ + i_ * 8),       \
                (__attribute__((address_space(3))) u32*)&T[bufi][i_ * 8], 16, 0, 0); \
    } while (0)

    STAGE(0, 0);
    __syncthreads();

    int buf = 0;
    for (int p = 0; p < 18; ++p) {
        if (p + 1 < 18) STAGE(p + 1, buf ^ 1);         // prefetch next half-slab

        const int kwx = p >> 1, ks = p & 1;
        const u16* wo = wg + (size_t)(kwx * 9) * 4096 + ks * 512;   // + sub*4096 + rt*1024 + l*8
        const u16* Tb = T[buf];

        bf16x8 a[2][4];
#pragma unroll
        for (int rt = 0; rt < 4; ++rt)
            a[0][rt] = *(const bf16x8*)(wo + (size_t)rt * 1024 + l * 8);

#pragma unroll
        for (int sub = 0; sub < 9; ++sub) {            // full unroll: a[sub&1] static
            if (sub + 1 < 9) {
                const u16* wn = wo + (size_t)(sub + 1) * 4096;
#pragma unroll
                for (int rt = 0; rt < 4; ++rt)
                    a[(sub + 1) & 1][rt] = *(const bf16x8*)(wn + (size_t)rt * 1024 + l * 8);
            }
            const int ky = sub / 3, kz = sub - ky * 3;
#pragma unroll
            for (int ct = 0; ct < 2; ++ct) {
                const int rem = (2 * wv + ct + ky) * 18 + ll + kz;
                const bf16x8 bf = *(const bf16x8*)&Tb[rem * 32 + lg * 8];
#pragma unroll
                for (int rt = 0; rt < 4; ++rt)
                    acc[rt][ct] = __builtin_amdgcn_mfma_f32_16x16x32_bf16(
                        a[sub & 1][rt], bf, acc[rt][ct], 0, 0, 0);
            }
        }
        __syncthreads();                               // drains prefetch vmcnt; buf swap safe
        buf ^= 1;
    }
#undef STAGE

    float* ob = out + (size_t)b * 4194304 + (size_t)w * 4096 + (size_t)x * 256;
#pragma unroll
    for (int rt = 0; rt < 4; ++rt) {
        const int co0 = rt * 16 + 4 * lg;
#pragma unroll
        for (int ct = 0; ct < 2; ++ct) {
            const int base = (2 * wv + ct) * 16 + ll;
#pragma unroll
            for (int r = 0; r < 4; ++r)
                ob[(size_t)(co0 + r) * 65536 + base] = acc[rt][ct][r];
        }
    }
}

// ---------------- fallback (round-1 kernel, used if ws too small) ----------------
__global__ __launch_bounds__(512, 2)
void conv4d_mfma(const float* __restrict__ in, const float* __restrict__ ker,
                 float* __restrict__ out) {
    __shared__ unsigned short T[18 * 18 * 64];
    __shared__ unsigned short Wt[2][64 * 64];
    const int bx = blockIdx.x;
    const int b = bx >> 8, wsp = (bx >> 4) & 15, x = bx & 15;
    const int t = threadIdx.x, wv = t >> 6, l = t & 63;
    const int lg = l >> 4, ll = l & 15;
    const float* inb = in + (size_t)b * 6718464 + wsp * 5832 + x * 324;
    f32x4 acc[4][2];
#pragma unroll
    for (int i = 0; i < 4; ++i)
#pragma unroll
        for (int j = 0; j < 2; ++j) acc[i][j] = (f32x4){0.f, 0.f, 0.f, 0.f};
#pragma unroll
    for (int f0 = 0; f0 < 4096; f0 += 512) {
        const int f = f0 + t, ci = f >> 6, co = f & 63;
        Wt[0][co * 64 + ((((ci >> 3) ^ (co & 7)) << 3) | (ci & 7))] = f2bf(ker[f]);
    }
    for (int off = 0; off < 81; ++off) {
        const int sub = off % 9;
        if (sub == 0) {
            const int kw = off / 27, kx = (off / 9) % 3;
            const float* p = inb + kw * 5832 + kx * 324;
            for (int f = t; f < 18 * 18 * 64; f += 512) {
                const int ci = f / 324, rem = f - ci * 324, zp = rem % 18;
                T[rem * 64 + ((((ci >> 3) ^ (zp & 7)) << 3) | (ci & 7))] =
                    f2bf(p[(size_t)ci * 104976 + rem]);
            }
        }
        if (off + 1 < 81) {
            const float* p = ker + (off + 1) * 4096;
            unsigned short* wb = Wt[(off + 1) & 1];
#pragma unroll
            for (int f0 = 0; f0 < 4096; f0 += 512) {
                const int f = f0 + t, ci = f >> 6, co = f & 63;
                wb[co * 64 + ((((ci >> 3) ^ (co & 7)) << 3) | (ci & 7))] = f2bf(p[f]);
            }
        }
        if (sub == 0) __syncthreads();
        const int ky = sub / 3, kz = sub - ky * 3;
        const int zp = ll + kz, zs = zp & 7;
#pragma unroll
        for (int ks = 0; ks < 2; ++ks) {
            bf16x8 af[4];
#pragma unroll
            for (int rt = 0; rt < 4; ++rt)
                af[rt] = *(const bf16x8*)&Wt[off & 1][(rt * 16 + ll) * 64 + (((lg + 4 * ks) ^ (ll & 7)) << 3)];
#pragma unroll
            for (int ct = 0; ct < 2; ++ct) {
                const int rem = (2 * wv + ct + ky) * 18 + zp;
                const bf16x8 bfr = *(const bf16x8*)&T[rem * 64 + (((lg + 4 * ks) ^ zs) << 3)];
#pragma unroll
                for (int rt = 0; rt < 4; ++rt)
                    acc[rt][ct] = __builtin_amdgcn_mfma_f32_16x16x32_bf16(af[rt], bfr, acc[rt][ct], 0, 0, 0);
            }
        }
        __syncthreads();
    }
    float* ob = out + (size_t)b * 4194304 + wsp * 4096 + x * 256;
#pragma unroll
    for (int rt = 0; rt < 4; ++rt) {
        const int co0 = rt * 16 + 4 * lg;
#pragma unroll
        for (int ct = 0; ct < 2; ++ct) {
            const int base = (2 * wv + ct) * 16 + ll;
#pragma unroll
            for (int r = 0; r < 4; ++r)
                ob[(size_t)(co0 + r) * 65536 + base] = acc[rt][ct][r];
        }
    }
}

extern "C" void kernel_launch(void* const* d_in, const int* in_sizes, int n_in,
                              void* d_out, int out_size, void* d_ws, size_t ws_size,
                              hipStream_t stream) {
    const float* in  = (const float*)d_in[0];
    const float* ker = (const float*)d_in[1];
    float* out = (float*)d_out;
    if (ws_size >= (size_t)WS_NEEDED) {
        u16* wg = (u16*)d_ws;
        u16* s  = (u16*)((char*)d_ws + S_OFF_BYTES);
        wprep<<<dim3(162), dim3(256), 0, stream>>>(ker, wg);
        sprep<<<dim3(648), dim3(256), 0, stream>>>(in, s);
        conv4d_main<<<dim3(512), dim3(512), 0, stream>>>(wg, s, out);
    } else {
        conv4d_mfma<<<dim3(512), dim3(512), 0, stream>>>(in, ker, out);
    }
}

// Round 5
// 113.809 us; speedup vs baseline: 1.0094x; 1.0064x over previous
//
#include <hip/hip_runtime.h>

// Conv4d implicit GEMM, v5.
// wprep: weights f32 -> bf16 in MFMA-fragment order Wg[off][rt][ks][lane][8].
// sprep: input f32 -> bf16 half-slabs S[(b,w',x')][ks][rem=y'*18+z'][32 ci],
//        granule-swizzled: 16B granule g of row rem stored at g ^ ((rem>>1)&3)
//        -> main-kernel ds_read_b128 is 2-way max (free) instead of 8-way.
// main:  block = (b,w,x), 512 thr / 8 waves, wave owns y-tiles {2wv, 2wv+1}.
//        18 phases (9 kwx x 2 ks); half-slab (20.7KB) double-buffered via
//        global_load_lds (linear dest, pre-swizzled source). 2 blocks/CU.
//        A-frags: global->VGPR 3-deep ring (2 subs ahead), all-wave-identical
//        addresses -> L1 broadcast. setprio(1) around each 8-MFMA cluster.

typedef __attribute__((ext_vector_type(8))) short bf16x8;
typedef __attribute__((ext_vector_type(4))) float f32x4;
typedef __attribute__((ext_vector_type(8))) unsigned short ushort8;
typedef unsigned short u16;
typedef unsigned int u32;

#define S_OFF_BYTES 663552u          // Wg = 81*4096 u16
#define WS_NEEDED   27537408u        // + 648 slabs * 41472 B

__device__ __forceinline__ u16 f2bf(float f) {
    u32 u = __float_as_uint(f);
    u += 0x7FFFu + ((u >> 16) & 1u);   // RNE
    return (u16)(u >> 16);
}

// ---------------- pre-pass 1: weights ----------------
__global__ __launch_bounds__(256) void wprep(const float* __restrict__ ker, u16* __restrict__ wg) {
    const int g = blockIdx.x * 256 + threadIdx.x;      // 0..41471
    const int l = g & 63, ks = (g >> 6) & 1, rt = (g >> 7) & 3, off = g >> 9;
    const int co  = rt * 16 + (l & 15);
    const int ci0 = ks * 32 + (l >> 4) * 8;
    const float* p = ker + (size_t)off * 4096 + co;
    ushort8 v;
#pragma unroll
    for (int e = 0; e < 8; ++e) v[e] = f2bf(p[(size_t)(ci0 + e) * 64]);
    *(ushort8*)(wg + (size_t)g * 8) = v;
}

// ---------------- pre-pass 2: input half-slabs (granule-swizzled) ----------------
__global__ __launch_bounds__(256) void sprep(const float* __restrict__ in, u16* __restrict__ s) {
    __shared__ u16 L[64 * 330];                        // [ci][rem padded]
    const int blk = blockIdx.x;                        // 648 = 2*18*18
    const int b = blk / 324, wx = blk - b * 324;
    const float* src = in + (size_t)b * 6718464 + (wx / 18) * 5832 + (wx % 18) * 324;
    const int t = threadIdx.x;
    for (int i = t; i < 5184; i += 256) {              // 64 ci * 81 float4
        const int ci = i / 81, j = i - ci * 81;
        float4 v = *(const float4*)(src + (size_t)ci * 104976 + j * 4);
        u32* q = (u32*)&L[ci * 330 + j * 4];
        q[0] = f2bf(v.x) | ((u32)f2bf(v.y) << 16);
        q[1] = f2bf(v.z) | ((u32)f2bf(v.w) << 16);
    }
    __syncthreads();
    u16* dst = s + (size_t)blk * 20736;                // [ks][rem][32 swizzled]
    for (int i = t; i < 2592; i += 256) {              // 2 ks * 324 rem * 4 granules
        const int ks = i / 1296, r4 = i - ks * 1296;
        const int rem = r4 >> 2, g = r4 & 3;
        ushort8 v;
#pragma unroll
        for (int e = 0; e < 8; ++e) v[e] = L[(ks * 32 + g * 8 + e) * 330 + rem];
        const int gp = g ^ ((rem >> 1) & 3);           // involution granule swizzle
        *(ushort8*)(dst + ks * 10368 + rem * 32 + gp * 8) = v;
    }
}

// ---------------- main ----------------
__global__ __launch_bounds__(512, 4)
void conv4d_main(const u16* __restrict__ wg, const u16* __restrict__ s, float* __restrict__ out) {
    __shared__ u16 T[2][324 * 32];                     // 2 x 20736 B half-slabs

    // bijective XCD swizzle (512 % 8 == 0)
    const int bid = blockIdx.x;
    const int bs  = (bid & 7) * 64 + (bid >> 3);
    const int b   = bs >> 8;
    const int w   = (bs >> 4) & 15;
    const int x   = bs & 15;

    const int t  = threadIdx.x, wv = t >> 6, l = t & 63;
    const int lg = l >> 4, ll = l & 15;

    f32x4 acc[4][2];
#pragma unroll
    for (int i = 0; i < 4; ++i)
#pragma unroll
        for (int j = 0; j < 2; ++j) acc[i][j] = (f32x4){0.f, 0.f, 0.f, 0.f};

    const u16* sb = s + (size_t)(b * 324 + w * 18 + x) * 20736;

#define STAGE(p, bufi)                                                               \
    do {                                                                             \
        const int kwx_ = (p) >> 1, ks_ = (p) & 1;                                    \
        const int kw_ = kwx_ / 3, kx_ = kwx_ - kw_ * 3;                              \
        const u16* src_ = sb + (size_t)(kw_ * 18 + kx_) * 20736 + ks_ * 10368;       \
        for (int i_ = t; i_ < 1296; i_ += 512)                                       \
            __builtin_amdgcn_global_load_lds(                                        \
                (const __attribute__((address_space(1))) u32*)(src_ + i_ * 8),       \
                (__attribute__((address_space(3))) u32*)&T[bufi][i_ * 8], 16, 0, 0); \
    } while (0)

    STAGE(0, 0);
    __syncthreads();

    int buf = 0;
    for (int p = 0; p < 18; ++p) {
        if (p + 1 < 18) STAGE(p + 1, buf ^ 1);         // prefetch next half-slab

        const int kwx = p >> 1, ks = p & 1;
        const u16* wo = wg + (size_t)(kwx * 9) * 4096 + ks * 512;
        const u16* Tb = T[buf];

        bf16x8 a[3][4];                                // 3-deep A ring (2 subs ahead)
#pragma unroll
        for (int rt = 0; rt < 4; ++rt) {
            a[0][rt] = *(const bf16x8*)(wo + (size_t)rt * 1024 + l * 8);
            a[1][rt] = *(const bf16x8*)(wo + 4096 + (size_t)rt * 1024 + l * 8);
        }

#pragma unroll
        for (int sub = 0; sub < 9; ++sub) {            // full unroll: ring idx static
            if (sub + 2 < 9) {
                const u16* wn = wo + (size_t)(sub + 2) * 4096;
#pragma unroll
                for (int rt = 0; rt < 4; ++rt)
                    a[(sub + 2) % 3][rt] = *(const bf16x8*)(wn + (size_t)rt * 1024 + l * 8);
            }
            const int ky = sub / 3, kz = sub - ky * 3;
            bf16x8 bfr[2];
#pragma unroll
            for (int ct = 0; ct < 2; ++ct) {
                const int rem = (2 * wv + ct + ky) * 18 + ll + kz;
                bfr[ct] = *(const bf16x8*)&Tb[rem * 32 + ((lg ^ ((rem >> 1) & 3)) << 3)];
            }
            __builtin_amdgcn_s_setprio(1);
#pragma unroll
            for (int ct = 0; ct < 2; ++ct)
#pragma unroll
                for (int rt = 0; rt < 4; ++rt)
                    acc[rt][ct] = __builtin_amdgcn_mfma_f32_16x16x32_bf16(
                        a[sub % 3][rt], bfr[ct], acc[rt][ct], 0, 0, 0);
            __builtin_amdgcn_s_setprio(0);
        }
        __syncthreads();                               // drains prefetch vmcnt; buf swap safe
        buf ^= 1;
    }
#undef STAGE

    float* ob = out + (size_t)b * 4194304 + (size_t)w * 4096 + (size_t)x * 256;
#pragma unroll
    for (int rt = 0; rt < 4; ++rt) {
        const int co0 = rt * 16 + 4 * lg;
#pragma unroll
        for (int ct = 0; ct < 2; ++ct) {
            const int base = (2 * wv + ct) * 16 + ll;
#pragma unroll
            for (int r = 0; r < 4; ++r)
                ob[(size_t)(co0 + r) * 65536 + base] = acc[rt][ct][r];
        }
    }
}

// ---------------- fallback (round-1 kernel, used if ws too small) ----------------
__global__ __launch_bounds__(512, 2)
void conv4d_mfma(const float* __restrict__ in, const float* __restrict__ ker,
                 float* __restrict__ out) {
    __shared__ unsigned short T[18 * 18 * 64];
    __shared__ unsigned short Wt[2][64 * 64];
    const int bx = blockIdx.x;
    const int b = bx >> 8, wsp = (bx >> 4) & 15, x = bx & 15;
    const int t = threadIdx.x, wv = t >> 6, l = t & 63;
    const int lg = l >> 4, ll = l & 15;
    const float* inb = in + (size_t)b * 6718464 + wsp * 5832 + x * 324;
    f32x4 acc[4][2];
#pragma unroll
    for (int i = 0; i < 4; ++i)
#pragma unroll
        for (int j = 0; j < 2; ++j) acc[i][j] = (f32x4){0.f, 0.f, 0.f, 0.f};
#pragma unroll
    for (int f0 = 0; f0 < 4096; f0 += 512) {
        const int f = f0 + t, ci = f >> 6, co = f & 63;
        Wt[0][co * 64 + ((((ci >> 3) ^ (co & 7)) << 3) | (ci & 7))] = f2bf(ker[f]);
    }
    for (int off = 0; off < 81; ++off) {
        const int sub = off % 9;
        if (sub == 0) {
            const int kw = off / 27, kx = (off / 9) % 3;
            const float* p = inb + kw * 5832 + kx * 324;
            for (int f = t; f < 18 * 18 * 64; f += 512) {
                const int ci = f / 324, rem = f - ci * 324, zp = rem % 18;
                T[rem * 64 + ((((ci >> 3) ^ (zp & 7)) << 3) | (ci & 7))] =
                    f2bf(p[(size_t)ci * 104976 + rem]);
            }
        }
        if (off + 1 < 81) {
            const float* p = ker + (off + 1) * 4096;
            unsigned short* wb = Wt[(off + 1) & 1];
#pragma unroll
            for (int f0 = 0; f0 < 4096; f0 += 512) {
                const int f = f0 + t, ci = f >> 6, co = f & 63;
                wb[co * 64 + ((((ci >> 3) ^ (co & 7)) << 3) | (ci & 7))] = f2bf(p[f]);
            }
        }
        if (sub == 0) __syncthreads();
        const int ky = sub / 3, kz = sub - ky * 3;
        const int zp = ll + kz, zs = zp & 7;
#pragma unroll
        for (int ks = 0; ks < 2; ++ks) {
            bf16x8 af[4];
#pragma unroll
            for (int rt = 0; rt < 4; ++rt)
                af[rt] = *(const bf16x8*)&Wt[off & 1][(rt * 16 + ll) * 64 + (((lg + 4 * ks) ^ (ll & 7)) << 3)];
#pragma unroll
            for (int ct = 0; ct < 2; ++ct) {
                const int rem = (2 * wv + ct + ky) * 18 + zp;
                const bf16x8 bfr = *(const bf16x8*)&T[rem * 64 + (((lg + 4 * ks) ^ zs) << 3)];
#pragma unroll
                for (int rt = 0; rt < 4; ++rt)
                    acc[rt][ct] = __builtin_amdgcn_mfma_f32_16x16x32_bf16(af[rt], bfr, acc[rt][ct], 0, 0, 0);
            }
        }
        __syncthreads();
    }
    float* ob = out + (size_t)b * 4194304 + wsp * 4096 + x * 256;
#pragma unroll
    for (int rt = 0; rt < 4; ++rt) {
        const int co0 = rt * 16 + 4 * lg;
#pragma unroll
        for (int ct = 0; ct < 2; ++ct) {
            const int base = (2 * wv + ct) * 16 + ll;
#pragma unroll
            for (int r = 0; r < 4; ++r)
                ob[(size_t)(co0 + r) * 65536 + base] = acc[rt][ct][r];
        }
    }
}

extern "C" void kernel_launch(void* const* d_in, const int* in_sizes, int n_in,
                              void* d_out, int out_size, void* d_ws, size_t ws_size,
                              hipStream_t stream) {
    const float* in  = (const float*)d_in[0];
    const float* ker = (const float*)d_in[1];
    float* out = (float*)d_out;
    if (ws_size >= (size_t)WS_NEEDED) {
        u16* wg = (u16*)d_ws;
        u16* s  = (u16*)((char*)d_ws + S_OFF_BYTES);
        wprep<<<dim3(162), dim3(256), 0, stream>>>(ker, wg);
        sprep<<<dim3(648), dim3(256), 0, stream>>>(in, s);
        conv4d_main<<<dim3(512), dim3(512), 0, stream>>>(wg, s, out);
    } else {
        conv4d_mfma<<<dim3(512), dim3(512), 0, stream>>>(in, ker, out);
    }
}

// Round 6
// 99.265 us; speedup vs baseline: 1.1573x; 1.1465x over previous
//
#include <hip/hip_runtime.h>

// Conv4d implicit GEMM, v6.
// wprep: weights f32 -> bf16 in MFMA-fragment order Wg[off][rt][ks][lane][8].
// sprep: input f32 -> bf16 half-slabs S[(b,w',x')][ks][rem=y'*18+z'][32 ci],
//        granule-swizzled: granule g of row rem at g ^ ((rem>>1)&3) (2-way max on read).
// main:  block = (b,w,x), 256 thr / 4 waves. Wave owns 4 rt (all 64 co) x 4 ct
//        (y-tiles 4wv..4wv+3) -> A-loads amortized over 16 MFMA/sub (VMEM pipe
//        was the round-5 wall: 10368 -> 5184 wave-loads/CU). 18 phases (9 kwx x 2 ks),
//        half-slab (20.7KB) double-buffered via global_load_lds. 2 blocks/CU.
//        A-frags: global->VGPR ring a[4][4], prefetch 3 subs (~240 cyc) ahead;
//        launch_bounds(256,2) so the ring actually stays in registers.

typedef __attribute__((ext_vector_type(8))) short bf16x8;
typedef __attribute__((ext_vector_type(4))) float f32x4;
typedef __attribute__((ext_vector_type(8))) unsigned short ushort8;
typedef unsigned short u16;
typedef unsigned int u32;

#define S_OFF_BYTES 663552u          // Wg = 81*4096 u16
#define WS_NEEDED   27537408u        // + 648 slabs * 41472 B

__device__ __forceinline__ u16 f2bf(float f) {
    u32 u = __float_as_uint(f);
    u += 0x7FFFu + ((u >> 16) & 1u);   // RNE
    return (u16)(u >> 16);
}

// ---------------- pre-pass 1: weights ----------------
__global__ __launch_bounds__(256) void wprep(const float* __restrict__ ker, u16* __restrict__ wg) {
    const int g = blockIdx.x * 256 + threadIdx.x;      // 0..41471
    const int l = g & 63, ks = (g >> 6) & 1, rt = (g >> 7) & 3, off = g >> 9;
    const int co  = rt * 16 + (l & 15);
    const int ci0 = ks * 32 + (l >> 4) * 8;
    const float* p = ker + (size_t)off * 4096 + co;
    ushort8 v;
#pragma unroll
    for (int e = 0; e < 8; ++e) v[e] = f2bf(p[(size_t)(ci0 + e) * 64]);
    *(ushort8*)(wg + (size_t)g * 8) = v;
}

// ---------------- pre-pass 2: input half-slabs (granule-swizzled) ----------------
__global__ __launch_bounds__(256) void sprep(const float* __restrict__ in, u16* __restrict__ s) {
    __shared__ u16 L[64 * 330];                        // [ci][rem padded]
    const int blk = blockIdx.x;                        // 648 = 2*18*18
    const int b = blk / 324, wx = blk - b * 324;
    const float* src = in + (size_t)b * 6718464 + (wx / 18) * 5832 + (wx % 18) * 324;
    const int t = threadIdx.x;
    for (int i = t; i < 5184; i += 256) {              // 64 ci * 81 float4
        const int ci = i / 81, j = i - ci * 81;
        float4 v = *(const float4*)(src + (size_t)ci * 104976 + j * 4);
        u32* q = (u32*)&L[ci * 330 + j * 4];
        q[0] = f2bf(v.x) | ((u32)f2bf(v.y) << 16);
        q[1] = f2bf(v.z) | ((u32)f2bf(v.w) << 16);
    }
    __syncthreads();
    u16* dst = s + (size_t)blk * 20736;                // [ks][rem][32 swizzled]
    for (int i = t; i < 2592; i += 256) {              // 2 ks * 324 rem * 4 granules
        const int ks = i / 1296, r4 = i - ks * 1296;
        const int rem = r4 >> 2, g = r4 & 3;
        ushort8 v;
#pragma unroll
        for (int e = 0; e < 8; ++e) v[e] = L[(ks * 32 + g * 8 + e) * 330 + rem];
        const int gp = g ^ ((rem >> 1) & 3);           // involution granule swizzle
        *(ushort8*)(dst + ks * 10368 + rem * 32 + gp * 8) = v;
    }
}

// ---------------- main ----------------
__global__ __launch_bounds__(256, 2)
void conv4d_main(const u16* __restrict__ wg, const u16* __restrict__ s, float* __restrict__ out) {
    __shared__ u16 T[2][324 * 32];                     // 2 x 20736 B half-slabs

    // bijective XCD swizzle (512 % 8 == 0)
    const int bid = blockIdx.x;
    const int bs  = (bid & 7) * 64 + (bid >> 3);
    const int b   = bs >> 8;
    const int w   = (bs >> 4) & 15;
    const int x   = bs & 15;

    const int t  = threadIdx.x, wv = t >> 6, l = t & 63;
    const int lg = l >> 4, ll = l & 15;

    f32x4 acc[4][4];
#pragma unroll
    for (int i = 0; i < 4; ++i)
#pragma unroll
        for (int j = 0; j < 4; ++j) acc[i][j] = (f32x4){0.f, 0.f, 0.f, 0.f};

    const u16* sb = s + (size_t)(b * 324 + w * 18 + x) * 20736;

#define STAGE(p, bufi)                                                               \
    do {                                                                             \
        const int kwx_ = (p) >> 1, ks_ = (p) & 1;                                    \
        const int kw_ = kwx_ / 3, kx_ = kwx_ - kw_ * 3;                              \
        const u16* src_ = sb + (size_t)(kw_ * 18 + kx_) * 20736 + ks_ * 10368;       \
        for (int i_ = t; i_ < 1296; i_ += 256)                                       \
            __builtin_amdgcn_global_load_lds(                                        \
                (const __attribute__((address_space(1))) u32*)(src_ + i_ * 8),       \
                (__attribute__((address_space(3))) u32*)&T[bufi][i_ * 8], 16, 0, 0); \
    } while (0)

    STAGE(0, 0);
    __syncthreads();

    int buf = 0;
    for (int p = 0; p < 18; ++p) {
        if (p + 1 < 18) STAGE(p + 1, buf ^ 1);         // prefetch next half-slab

        const int kwx = p >> 1, ks = p & 1;
        const u16* wo = wg + (size_t)(kwx * 9) * 4096 + ks * 512;
        const u16* Tb = T[buf];

        bf16x8 a[4][4];                                // 4-deep A ring (3 subs ahead)
#pragma unroll
        for (int i = 0; i < 3; ++i)
#pragma unroll
            for (int rt = 0; rt < 4; ++rt)
                a[i][rt] = *(const bf16x8*)(wo + (size_t)i * 4096 + (size_t)rt * 1024 + l * 8);

#pragma unroll
        for (int sub = 0; sub < 9; ++sub) {            // full unroll: ring idx static
            if (sub + 3 < 9) {
                const u16* wn = wo + (size_t)(sub + 3) * 4096;
#pragma unroll
                for (int rt = 0; rt < 4; ++rt)
                    a[(sub + 3) & 3][rt] = *(const bf16x8*)(wn + (size_t)rt * 1024 + l * 8);
            }
            const int ky = sub / 3, kz = sub - ky * 3;
            bf16x8 bfr[4];
#pragma unroll
            for (int ct = 0; ct < 4; ++ct) {
                const int rem = (4 * wv + ct + ky) * 18 + ll + kz;
                bfr[ct] = *(const bf16x8*)&Tb[rem * 32 + ((lg ^ ((rem >> 1) & 3)) << 3)];
            }
            __builtin_amdgcn_s_setprio(1);
#pragma unroll
            for (int ct = 0; ct < 4; ++ct)
#pragma unroll
                for (int rt = 0; rt < 4; ++rt)
                    acc[rt][ct] = __builtin_amdgcn_mfma_f32_16x16x32_bf16(
                        a[sub & 3][rt], bfr[ct], acc[rt][ct], 0, 0, 0);
            __builtin_amdgcn_s_setprio(0);
        }
        __syncthreads();                               // drains prefetch vmcnt; buf swap safe
        buf ^= 1;
    }
#undef STAGE

    float* ob = out + (size_t)b * 4194304 + (size_t)w * 4096 + (size_t)x * 256;
#pragma unroll
    for (int rt = 0; rt < 4; ++rt) {
        const int co0 = rt * 16 + 4 * lg;
#pragma unroll
        for (int ct = 0; ct < 4; ++ct) {
            const int base = (4 * wv + ct) * 16 + ll;
#pragma unroll
            for (int r = 0; r < 4; ++r)
                ob[(size_t)(co0 + r) * 65536 + base] = acc[rt][ct][r];
        }
    }
}

// ---------------- fallback (round-1 kernel, used if ws too small) ----------------
__global__ __launch_bounds__(512, 2)
void conv4d_mfma(const float* __restrict__ in, const float* __restrict__ ker,
                 float* __restrict__ out) {
    __shared__ unsigned short T[18 * 18 * 64];
    __shared__ unsigned short Wt[2][64 * 64];
    const int bx = blockIdx.x;
    const int b = bx >> 8, wsp = (bx >> 4) & 15, x = bx & 15;
    const int t = threadIdx.x, wv = t >> 6, l = t & 63;
    const int lg = l >> 4, ll = l & 15;
    const float* inb = in + (size_t)b * 6718464 + wsp * 5832 + x * 324;
    f32x4 acc[4][2];
#pragma unroll
    for (int i = 0; i < 4; ++i)
#pragma unroll
        for (int j = 0; j < 2; ++j) acc[i][j] = (f32x4){0.f, 0.f, 0.f, 0.f};
#pragma unroll
    for (int f0 = 0; f0 < 4096; f0 += 512) {
        const int f = f0 + t, ci = f >> 6, co = f & 63;
        Wt[0][co * 64 + ((((ci >> 3) ^ (co & 7)) << 3) | (ci & 7))] = f2bf(ker[f]);
    }
    for (int off = 0; off < 81; ++off) {
        const int sub = off % 9;
        if (sub == 0) {
            const int kw = off / 27, kx = (off / 9) % 3;
            const float* p = inb + kw * 5832 + kx * 324;
            for (int f = t; f < 18 * 18 * 64; f += 512) {
                const int ci = f / 324, rem = f - ci * 324, zp = rem % 18;
                T[rem * 64 + ((((ci >> 3) ^ (zp & 7)) << 3) | (ci & 7))] =
                    f2bf(p[(size_t)ci * 104976 + rem]);
            }
        }
        if (off + 1 < 81) {
            const float* p = ker + (off + 1) * 4096;
            unsigned short* wb = Wt[(off + 1) & 1];
#pragma unroll
            for (int f0 = 0; f0 < 4096; f0 += 512) {
                const int f = f0 + t, ci = f >> 6, co = f & 63;
                wb[co * 64 + ((((ci >> 3) ^ (co & 7)) << 3) | (ci & 7))] = f2bf(p[f]);
            }
        }
        if (sub == 0) __syncthreads();
        const int ky = sub / 3, kz = sub - ky * 3;
        const int zp = ll + kz, zs = zp & 7;
#pragma unroll
        for (int ks = 0; ks < 2; ++ks) {
            bf16x8 af[4];
#pragma unroll
            for (int rt = 0; rt < 4; ++rt)
                af[rt] = *(const bf16x8*)&Wt[off & 1][(rt * 16 + ll) * 64 + (((lg + 4 * ks) ^ (ll & 7)) << 3)];
#pragma unroll
            for (int ct = 0; ct < 2; ++ct) {
                const int rem = (2 * wv + ct + ky) * 18 + zp;
                const bf16x8 bfr = *(const bf16x8*)&T[rem * 64 + (((lg + 4 * ks) ^ zs) << 3)];
#pragma unroll
                for (int rt = 0; rt < 4; ++rt)
                    acc[rt][ct] = __builtin_amdgcn_mfma_f32_16x16x32_bf16(af[rt], bfr, acc[rt][ct], 0, 0, 0);
            }
        }
        __syncthreads();
    }
    float* ob = out + (size_t)b * 4194304 + wsp * 4096 + x * 256;
#pragma unroll
    for (int rt = 0; rt < 4; ++rt) {
        const int co0 = rt * 16 + 4 * lg;
#pragma unroll
        for (int ct = 0; ct < 2; ++ct) {
            const int base = (2 * wv + ct) * 16 + ll;
#pragma unroll
            for (int r = 0; r < 4; ++r)
                ob[(size_t)(co0 + r) * 65536 + base] = acc[rt][ct][r];
        }
    }
}

extern "C" void kernel_launch(void* const* d_in, const int* in_sizes, int n_in,
                              void* d_out, int out_size, void* d_ws, size_t ws_size,
                              hipStream_t stream) {
    const float* in  = (const float*)d_in[0];
    const float* ker = (const float*)d_in[1];
    float* out = (float*)d_out;
    if (ws_size >= (size_t)WS_NEEDED) {
        u16* wg = (u16*)d_ws;
        u16* s  = (u16*)((char*)d_ws + S_OFF_BYTES);
        wprep<<<dim3(162), dim3(256), 0, stream>>>(ker, wg);
        sprep<<<dim3(648), dim3(256), 0, stream>>>(in, s);
        conv4d_main<<<dim3(512), dim3(256), 0, stream>>>(wg, s, out);
    } else {
        conv4d_mfma<<<dim3(512), dim3(512), 0, stream>>>(in, ker, out);
    }
}

// Round 7
// 99.044 us; speedup vs baseline: 1.1599x; 1.0022x over previous
//
#include <hip/hip_runtime.h>

// Conv4d implicit GEMM, v7.
// wprep: weights f32 -> bf16 in MFMA-fragment order Wg[off][rt][ks][lane][8].
// sprep: input f32 -> bf16 half-slabs S[(b,w',x')][ks][rem=y'*18+z'][32 ci],
//        granule-swizzled: granule g of row rem at g ^ ((rem>>1)&3) (2-way max on read).
// main:  block = (b,w,x), 512 thr / 8 waves. Wave = (sp-group g = wv&3: y-tiles 4g..4g+3,
//        ci-half ks = wv>>2). Each MFMA(16x16x32) eats exactly one 32-ci half-slab, so
//        ks-waves accumulate independent partials; wave-pairs reduce via LDS at the end.
//        -> 4096 total waves = 16 waves/CU = 4/SIMD (v6 had 8/CU: zero pipe overlap).
//        Half-slab ring R[4] (83KB): tick t: ks0 computes h=2t, ks1 computes h=2t-1
//        (one-kwx lag), stage h=2t+1 & 2t+2. One barrier per tick. launch_bounds(512,4)
//        caps VGPR at 128 so 2 blocks/CU co-reside.

typedef __attribute__((ext_vector_type(8))) short bf16x8;
typedef __attribute__((ext_vector_type(4))) float f32x4;
typedef __attribute__((ext_vector_type(8))) unsigned short ushort8;
typedef unsigned short u16;
typedef unsigned int u32;

#define S_OFF_BYTES 663552u          // Wg = 81*4096 u16
#define WS_NEEDED   27537408u        // + 648 slabs * 41472 B

__device__ __forceinline__ u16 f2bf(float f) {
    u32 u = __float_as_uint(f);
    u += 0x7FFFu + ((u >> 16) & 1u);   // RNE
    return (u16)(u >> 16);
}

// ---------------- pre-pass 1: weights ----------------
__global__ __launch_bounds__(256) void wprep(const float* __restrict__ ker, u16* __restrict__ wg) {
    const int g = blockIdx.x * 256 + threadIdx.x;      // 0..41471
    const int l = g & 63, ks = (g >> 6) & 1, rt = (g >> 7) & 3, off = g >> 9;
    const int co  = rt * 16 + (l & 15);
    const int ci0 = ks * 32 + (l >> 4) * 8;
    const float* p = ker + (size_t)off * 4096 + co;
    ushort8 v;
#pragma unroll
    for (int e = 0; e < 8; ++e) v[e] = f2bf(p[(size_t)(ci0 + e) * 64]);
    *(ushort8*)(wg + (size_t)g * 8) = v;
}

// ---------------- pre-pass 2: input half-slabs (granule-swizzled) ----------------
__global__ __launch_bounds__(256) void sprep(const float* __restrict__ in, u16* __restrict__ s) {
    __shared__ u16 L[64 * 330];                        // [ci][rem padded]
    const int blk = blockIdx.x;                        // 648 = 2*18*18
    const int b = blk / 324, wx = blk - b * 324;
    const float* src = in + (size_t)b * 6718464 + (wx / 18) * 5832 + (wx % 18) * 324;
    const int t = threadIdx.x;
    for (int i = t; i < 5184; i += 256) {              // 64 ci * 81 float4
        const int ci = i / 81, j = i - ci * 81;
        float4 v = *(const float4*)(src + (size_t)ci * 104976 + j * 4);
        u32* q = (u32*)&L[ci * 330 + j * 4];
        q[0] = f2bf(v.x) | ((u32)f2bf(v.y) << 16);
        q[1] = f2bf(v.z) | ((u32)f2bf(v.w) << 16);
    }
    __syncthreads();
    u16* dst = s + (size_t)blk * 20736;                // [ks][rem][32 swizzled]
    for (int i = t; i < 2592; i += 256) {              // 2 ks * 324 rem * 4 granules
        const int ks = i / 1296, r4 = i - ks * 1296;
        const int rem = r4 >> 2, g = r4 & 3;
        ushort8 v;
#pragma unroll
        for (int e = 0; e < 8; ++e) v[e] = L[(ks * 32 + g * 8 + e) * 330 + rem];
        const int gp = g ^ ((rem >> 1) & 3);           // involution granule swizzle
        *(ushort8*)(dst + ks * 10368 + rem * 32 + gp * 8) = v;
    }
}

// ---------------- main ----------------
__global__ __launch_bounds__(512, 4)
void conv4d_main(const u16* __restrict__ wg, const u16* __restrict__ s, float* __restrict__ out) {
    __shared__ u16 R[4][324 * 32];                     // 4-slot half-slab ring, 82944 B

    // bijective XCD swizzle (512 % 8 == 0)
    const int bid = blockIdx.x;
    const int bs  = (bid & 7) * 64 + (bid >> 3);
    const int b   = bs >> 8;
    const int w   = (bs >> 4) & 15;
    const int x   = bs & 15;

    const int tid = threadIdx.x, wv = tid >> 6, l = tid & 63;
    const int ks  = wv >> 2;           // ci-half this wave owns
    const int g   = wv & 3;            // sp-group: y-tiles 4g..4g+3
    const int lg  = l >> 4, ll = l & 15;

    f32x4 acc[4][4];
#pragma unroll
    for (int i = 0; i < 4; ++i)
#pragma unroll
        for (int j = 0; j < 4; ++j) acc[i][j] = (f32x4){0.f, 0.f, 0.f, 0.f};

    const u16* sb = s + (size_t)(b * 324 + w * 18 + x) * 20736;

    // half-slab h: kwx = h>>1 (kw*3+kx), ks-half = h&1
#define STAGE_H(h)                                                                   \
    do {                                                                             \
        if ((h) <= 17) {                                                             \
            const int kwx_ = (h) >> 1, ksh_ = (h) & 1;                               \
            const int kw_ = kwx_ / 3, kx_ = kwx_ - kw_ * 3;                          \
            const u16* src_ = sb + (size_t)(kw_ * 18 + kx_) * 20736 + ksh_ * 10368;  \
            u16* dst_ = &R[(h) & 3][0];                                              \
            for (int i_ = tid; i_ < 1296; i_ += 512)                                 \
                __builtin_amdgcn_global_load_lds(                                    \
                    (const __attribute__((address_space(1))) u32*)(src_ + i_ * 8),   \
                    (__attribute__((address_space(3))) u32*)(dst_ + i_ * 8),         \
                    16, 0, 0);                                                       \
        }                                                                            \
    } while (0)

    STAGE_H(0);
    __syncthreads();

    for (int t = 0; t < 10; ++t) {
        STAGE_H(2 * t + 1);                            // prefetch (read next tick)
        STAGE_H(2 * t + 2);

        const int h = 2 * t - ks;                      // ks0: h=2t; ks1: h=2t-1 (lags one kwx)
        if (h >= 0 && h <= 17) {
            const int kwx = h >> 1;
            const u16* Tb = R[h & 3];
            const u16* wo = wg + (size_t)(kwx * 9) * 4096 + ks * 512;

            bf16x8 a[2][4];                            // 2-deep A ring (ping-pong)
#pragma unroll
            for (int rt = 0; rt < 4; ++rt)
                a[0][rt] = *(const bf16x8*)(wo + (size_t)rt * 1024 + l * 8);

#pragma unroll
            for (int sub = 0; sub < 9; ++sub) {        // full unroll: ring idx static
                if (sub + 1 < 9) {
                    const u16* wn = wo + (size_t)(sub + 1) * 4096;
#pragma unroll
                    for (int rt = 0; rt < 4; ++rt)
                        a[(sub + 1) & 1][rt] = *(const bf16x8*)(wn + (size_t)rt * 1024 + l * 8);
                }
                const int ky = sub / 3, kz = sub - ky * 3;
                bf16x8 bfr[4];
#pragma unroll
                for (int ct = 0; ct < 4; ++ct) {
                    const int rem = (4 * g + ct + ky) * 18 + ll + kz;
                    bfr[ct] = *(const bf16x8*)&Tb[rem * 32 + ((lg ^ ((rem >> 1) & 3)) << 3)];
                }
                __builtin_amdgcn_s_setprio(1);
#pragma unroll
                for (int ct = 0; ct < 4; ++ct)
#pragma unroll
                    for (int rt = 0; rt < 4; ++rt)
                        acc[rt][ct] = __builtin_amdgcn_mfma_f32_16x16x32_bf16(
                            a[sub & 1][rt], bfr[ct], acc[rt][ct], 0, 0, 0);
                __builtin_amdgcn_s_setprio(0);
            }
        }
        __syncthreads();                               // drains stage vmcnt; ring reuse safe
    }
#undef STAGE_H

    // epilogue: ks1 waves dump partials to LDS; ks0 waves add + store
    float* rbuf = (float*)&R[0][0];                    // 64KB of the 83KB ring
    if (ks == 1) {
#pragma unroll
        for (int rt = 0; rt < 4; ++rt)
#pragma unroll
            for (int ct = 0; ct < 4; ++ct)
                *(f32x4*)&rbuf[g * 4096 + (rt * 4 + ct) * 256 + l * 4] = acc[rt][ct];
    }
    __syncthreads();
    if (ks == 0) {
        float* ob = out + (size_t)b * 4194304 + (size_t)w * 4096 + (size_t)x * 256;
#pragma unroll
        for (int rt = 0; rt < 4; ++rt) {
            const int co0 = rt * 16 + 4 * lg;
#pragma unroll
            for (int ct = 0; ct < 4; ++ct) {
                f32x4 v = *(const f32x4*)&rbuf[g * 4096 + (rt * 4 + ct) * 256 + l * 4];
                v = v + acc[rt][ct];
                const int base = (4 * g + ct) * 16 + ll;
#pragma unroll
                for (int r = 0; r < 4; ++r)
                    ob[(size_t)(co0 + r) * 65536 + base] = v[r];
            }
        }
    }
}

// ---------------- fallback (round-1 kernel, used if ws too small) ----------------
__global__ __launch_bounds__(512, 2)
void conv4d_mfma(const float* __restrict__ in, const float* __restrict__ ker,
                 float* __restrict__ out) {
    __shared__ unsigned short T[18 * 18 * 64];
    __shared__ unsigned short Wt[2][64 * 64];
    const int bx = blockIdx.x;
    const int b = bx >> 8, wsp = (bx >> 4) & 15, x = bx & 15;
    const int t = threadIdx.x, wv = t >> 6, l = t & 63;
    const int lg = l >> 4, ll = l & 15;
    const float* inb = in + (size_t)b * 6718464 + wsp * 5832 + x * 324;
    f32x4 acc[4][2];
#pragma unroll
    for (int i = 0; i < 4; ++i)
#pragma unroll
        for (int j = 0; j < 2; ++j) acc[i][j] = (f32x4){0.f, 0.f, 0.f, 0.f};
#pragma unroll
    for (int f0 = 0; f0 < 4096; f0 += 512) {
        const int f = f0 + t, ci = f >> 6, co = f & 63;
        Wt[0][co * 64 + ((((ci >> 3) ^ (co & 7)) << 3) | (ci & 7))] = f2bf(ker[f]);
    }
    for (int off = 0; off < 81; ++off) {
        const int sub = off % 9;
        if (sub == 0) {
            const int kw = off / 27, kx = (off / 9) % 3;
            const float* p = inb + kw * 5832 + kx * 324;
            for (int f = t; f < 18 * 18 * 64; f += 512) {
                const int ci = f / 324, rem = f - ci * 324, zp = rem % 18;
                T[rem * 64 + ((((ci >> 3) ^ (zp & 7)) << 3) | (ci & 7))] =
                    f2bf(p[(size_t)ci * 104976 + rem]);
            }
        }
        if (off + 1 < 81) {
            const float* p = ker + (off + 1) * 4096;
            unsigned short* wb = Wt[(off + 1) & 1];
#pragma unroll
            for (int f0 = 0; f0 < 4096; f0 += 512) {
                const int f = f0 + t, ci = f >> 6, co = f & 63;
                wb[co * 64 + ((((ci >> 3) ^ (co & 7)) << 3) | (ci & 7))] = f2bf(p[f]);
            }
        }
        if (sub == 0) __syncthreads();
        const int ky = sub / 3, kz = sub - ky * 3;
        const int zp = ll + kz, zs = zp & 7;
#pragma unroll
        for (int ks = 0; ks < 2; ++ks) {
            bf16x8 af[4];
#pragma unroll
            for (int rt = 0; rt < 4; ++rt)
                af[rt] = *(const bf16x8*)&Wt[off & 1][(rt * 16 + ll) * 64 + (((lg + 4 * ks) ^ (ll & 7)) << 3)];
#pragma unroll
            for (int ct = 0; ct < 2; ++ct) {
                const int rem = (2 * wv + ct + ky) * 18 + zp;
                const bf16x8 bfr = *(const bf16x8*)&T[rem * 64 + (((lg + 4 * ks) ^ zs) << 3)];
#pragma unroll
                for (int rt = 0; rt < 4; ++rt)
                    acc[rt][ct] = __builtin_amdgcn_mfma_f32_16x16x32_bf16(af[rt], bfr, acc[rt][ct], 0, 0, 0);
            }
        }
        __syncthreads();
    }
    float* ob = out + (size_t)b * 4194304 + wsp * 4096 + x * 256;
#pragma unroll
    for (int rt = 0; rt < 4; ++rt) {
        const int co0 = rt * 16 + 4 * lg;
#pragma unroll
        for (int ct = 0; ct < 2; ++ct) {
            const int base = (2 * wv + ct) * 16 + ll;
#pragma unroll
            for (int r = 0; r < 4; ++r)
                ob[(size_t)(co0 + r) * 65536 + base] = acc[rt][ct][r];
        }
    }
}

extern "C" void kernel_launch(void* const* d_in, const int* in_sizes, int n_in,
                              void* d_out, int out_size, void* d_ws, size_t ws_size,
                              hipStream_t stream) {
    const float* in  = (const float*)d_in[0];
    const float* ker = (const float*)d_in[1];
    float* out = (float*)d_out;
    if (ws_size >= (size_t)WS_NEEDED) {
        u16* wg = (u16*)d_ws;
        u16* s  = (u16*)((char*)d_ws + S_OFF_BYTES);
        wprep<<<dim3(162), dim3(256), 0, stream>>>(ker, wg);
        sprep<<<dim3(648), dim3(256), 0, stream>>>(in, s);
        conv4d_main<<<dim3(512), dim3(512), 0, stream>>>(wg, s, out);
    } else {
        conv4d_mfma<<<dim3(512), dim3(512), 0, stream>>>(in, ker, out);
    }
}